// Round 5
// baseline (220.601 us; speedup 1.0000x reference)
//
#include <hip/hip_runtime.h>
#include <math.h>

#define IMG 512
#define QO  255      // qconv pooled output dim
#define QP  256      // padded row stride of qout
#define C2H 125
#define C2S 128      // padded row stride of c2out
#define C3H 123
#define NB  256      // grid blocks (1 per CU, co-resident)
#define NT  256      // threads per block

// ---------------------------------------------------------------------------
// Register-level circuit evolution helpers (compile-time gate wiring).
// ---------------------------------------------------------------------------
template<int M_>
__device__ inline void rot_regs(float2* a, float2 U00, float2 U01, float2 U10, float2 U11) {
    #pragma unroll
    for (int s = 0; s < 16; ++s) {
        if (!(s & M_)) {
            float2 a0 = a[s], a1 = a[s | M_];
            a[s]      = make_float2(U00.x*a0.x - U00.y*a0.y + U01.x*a1.x - U01.y*a1.y,
                                    U00.x*a0.y + U00.y*a0.x + U01.x*a1.y + U01.y*a1.x);
            a[s | M_] = make_float2(U10.x*a0.x - U10.y*a0.y + U11.x*a1.x - U11.y*a1.y,
                                    U10.x*a0.y + U10.y*a0.x + U11.x*a1.y + U11.y*a1.x);
        }
    }
}
template<int MC, int MT>
__device__ inline void cnot_regs(float2* a) {
    #pragma unroll
    for (int s = 0; s < 16; ++s) {
        if ((s & MC) && !(s & MT)) {
            float2 t = a[s]; a[s] = a[s | MT]; a[s | MT] = t;
        }
    }
}
__device__ inline void rot_gate_params(float phi, float th, float om,
                                       float2& U00, float2& U01, float2& U10, float2& U11) {
    float ch, sh, ca, sa, cb, sb;
    __sincosf(0.5f * th, &sh, &ch);
    __sincosf(0.5f * (phi + om), &sa, &ca);
    __sincosf(0.5f * (phi - om), &sb, &cb);
    U00 = make_float2( ca*ch, -sa*ch);
    U01 = make_float2(-cb*sh, -sb*sh);
    U10 = make_float2( cb*sh, -sb*sh);
    U11 = make_float2( ca*ch,  sa*ch);
}

__device__ __constant__ int UP1[10] = {0,0,0,0,1,1,1,2,2,3};
__device__ __constant__ int UP2[10] = {0,1,2,3,1,2,3,2,3,3};

// one-shot grid barrier (bar zeroed by hipMemsetAsync before launch)
__device__ __forceinline__ void grid_barrier(int* bar) {
    __syncthreads();
    if (threadIdx.x == 0) {
        __threadfence();                               // agent release (L2 WB)
        if (atomicAdd(bar, 1) == NB - 1) {
            atomicAdd(bar, NB);                        // value -> 2*NB
        } else {
            while (__hip_atomic_load(bar, __ATOMIC_RELAXED,
                                     __HIP_MEMORY_SCOPE_AGENT) < 2 * NB)
                __builtin_amdgcn_s_sleep(8);
        }
        __threadfence();                               // agent acquire (L2 INV)
    }
    __syncthreads();
}

union SmemU {
    struct { float2 Ms[256]; float4 G4[100]; } A;   // 3648 B
    struct { float  W[2000]; float  B[20];  } Bs;   // 8080 B
    struct { float4 W4[180]; int    bm[64]; } C;    // 3136 B
    struct { float  hh[640]; float  h1[64]; } D;    // 2816 B
};

// ---------------------------------------------------------------------------
// The whole network in one launch.
// ws layout (floats): [0..15] barrier ints; [16..655] am; qout; c2out.
// ---------------------------------------------------------------------------
__global__ __launch_bounds__(NT) void fused_net(
        const float* __restrict__ img, const float* __restrict__ qw,
        const float* __restrict__ c2w, const float* __restrict__ c2b,
        const float* __restrict__ c3w, const float* __restrict__ c3b,
        const float* __restrict__ f1w, const float* __restrict__ f1b,
        const float* __restrict__ f2w, const float* __restrict__ f2b,
        float* __restrict__ ws, float* __restrict__ out) {
    __shared__ SmemU sm;
    int* bar    = (int*)ws;
    float* am   = ws + 16;
    float* qout = ws + 16 + 640;
    float* c2o  = qout + 4 * QP * QP;
    int tid = threadIdx.x;

    // ================= stage A: qconv + sigmoid∘maxpool2 =================
    if (tid < 16) {
        float2 a[16];
        #pragma unroll
        for (int s = 0; s < 16; ++s) a[s] = make_float2(s == tid ? 1.f : 0.f, 0.f);
        float2 U00, U01, U10, U11;
#define ROTG(L, W) rot_gate_params(qw[((L)*4+(W))*3+0], qw[((L)*4+(W))*3+1], qw[((L)*4+(W))*3+2], U00,U01,U10,U11); \
                   rot_regs<(1 << (3-(W)))>(a, U00, U01, U10, U11);
        ROTG(0,0) ROTG(0,1) ROTG(0,2) ROTG(0,3)
        cnot_regs<8,4>(a); cnot_regs<4,2>(a); cnot_regs<2,1>(a); cnot_regs<1,8>(a);
        ROTG(1,0) ROTG(1,1) ROTG(1,2) ROTG(1,3)
        cnot_regs<8,2>(a); cnot_regs<4,1>(a); cnot_regs<2,8>(a); cnot_regs<1,4>(a);
        ROTG(2,0) ROTG(2,1) ROTG(2,2) ROTG(2,3)
        cnot_regs<8,1>(a); cnot_regs<4,8>(a); cnot_regs<2,4>(a); cnot_regs<1,2>(a);
#undef ROTG
        int pc4 = __popc(tid) & 3;
        #pragma unroll
        for (int row = 0; row < 16; ++row) {
            float2 v = a[row], o;
            if      (pc4 == 0) o = v;
            else if (pc4 == 1) o = make_float2( v.y, -v.x);
            else if (pc4 == 2) o = make_float2(-v.x, -v.y);
            else               o = make_float2(-v.y,  v.x);
            sm.A.Ms[row * 16 + tid] = o;
        }
    }
    __syncthreads();
    if (tid < 100) {
        int al = tid / 10, be = tid - 10 * (tid / 10);
        int u = UP1[al], up = UP2[al], v = UP1[be], vp = UP2[be];
        float s0 = 0.f, s1 = 0.f, s2 = 0.f, s3 = 0.f;
        for (int ci = 0; ci < 2; ++ci) {
            if (ci == 1 && u == up) break;
            int a1 = ci ? up : u, a2 = ci ? u : up;
            for (int cj = 0; cj < 2; ++cj) {
                if (cj == 1 && v == vp) break;
                int b1 = cj ? vp : v, b2 = cj ? v : vp;
                int k = a1 * 4 + b1, kp = a2 * 4 + b2;
                #pragma unroll
                for (int r = 0; r < 16; ++r) {
                    float2 m1 = sm.A.Ms[r * 16 + k], m2 = sm.A.Ms[r * 16 + kp];
                    float p = m1.x * m2.x + m1.y * m2.y;
                    s0 += (r & 8) ? -p : p;
                    s1 += (r & 4) ? -p : p;
                    s2 += (r & 2) ? -p : p;
                    s3 += (r & 1) ? -p : p;
                }
            }
        }
        sm.A.G4[tid] = make_float4(s0, s1, s2, s3);
    }
    __syncthreads();

    {
        int gid = blockIdx.x * NT + tid;           // 65536 threads, 65025 pixels
        if (gid < QO * QO) {
            int i = gid / QO, j = gid - i * QO;
            int r0 = 2 * i, c0 = 2 * j;
            float cs[3][3], sn[3][3];
            #pragma unroll
            for (int rr = 0; rr < 3; ++rr)
                #pragma unroll
                for (int cc = 0; cc < 3; ++cc) {
                    float v = img[(r0 + rr) * IMG + c0 + cc];
                    __sincosf(0.5f * v, &sn[rr][cc], &cs[rr][cc]);
                }
            float tv[3][2][4];
            #pragma unroll
            for (int rr = 0; rr < 3; ++rr)
                #pragma unroll
                for (int pc = 0; pc < 2; ++pc) {
                    tv[rr][pc][0] = cs[rr][pc] * cs[rr][pc+1];
                    tv[rr][pc][1] = cs[rr][pc] * sn[rr][pc+1];
                    tv[rr][pc][2] = sn[rr][pc] * cs[rr][pc+1];
                    tv[rr][pc][3] = sn[rr][pc] * sn[rr][pc+1];
                }
            float mx0 = -1e30f, mx1 = -1e30f, mx2 = -1e30f, mx3 = -1e30f;
            #pragma unroll
            for (int pr = 0; pr < 2; ++pr) {
                #pragma unroll
                for (int pc = 0; pc < 2; ++pc) {
                    float q23[10];
                    #pragma unroll
                    for (int be = 0; be < 10; ++be)
                        q23[be] = tv[pr+1][pc][UP1[be]] * tv[pr+1][pc][UP2[be]];
                    float e0 = 0.f, e1 = 0.f, e2 = 0.f, e3 = 0.f;
                    #pragma unroll
                    for (int al = 0; al < 10; ++al) {
                        float pa = tv[pr][pc][UP1[al]] * tv[pr][pc][UP2[al]];
                        #pragma unroll
                        for (int be = 0; be < 10; ++be) {
                            float4 g = sm.A.G4[al * 10 + be];
                            float pq = pa * q23[be];
                            e0 = fmaf(g.x, pq, e0);
                            e1 = fmaf(g.y, pq, e1);
                            e2 = fmaf(g.z, pq, e2);
                            e3 = fmaf(g.w, pq, e3);
                        }
                    }
                    mx0 = fmaxf(mx0, e0); mx1 = fmaxf(mx1, e1);
                    mx2 = fmaxf(mx2, e2); mx3 = fmaxf(mx3, e3);
                }
            }
            int o = i * QP + j;
            qout[0 * QP * QP + o] = 1.f / (1.f + __expf(-mx0));
            qout[1 * QP * QP + o] = 1.f / (1.f + __expf(-mx1));
            qout[2 * QP * QP + o] = 1.f / (1.f + __expf(-mx2));
            qout[3 * QP * QP + o] = 1.f / (1.f + __expf(-mx3));
        }
    }
    grid_barrier(bar + 0);

    // ================= stage B: conv2 + bias + relu + maxpool2 ===========
    for (int e = tid; e < 2000; e += NT) sm.Bs.W[e] = c2w[e];
    if (tid < 20) sm.Bs.B[tid] = c2b[tid];
    __syncthreads();
    for (int e = blockIdx.x * NT + tid; e < 20 * C2H * C2H; e += NB * NT) {
        int oc = e / (C2H * C2H);
        int sp = e - oc * (C2H * C2H);
        int i = sp / C2H, j = sp - i * C2H;
        float a00 = 0.f, a01 = 0.f, a10 = 0.f, a11 = 0.f;
        #pragma unroll
        for (int ic = 0; ic < 4; ++ic) {
            const float* ip = qout + ic * QP * QP + (2 * i) * QP + 2 * j;
            float win[6][6];
            #pragma unroll
            for (int y = 0; y < 6; ++y) {
                #pragma unroll
                for (int h = 0; h < 3; ++h) {
                    float2 v = *(const float2*)(ip + y * QP + 2 * h);
                    win[y][2*h]   = v.x;
                    win[y][2*h+1] = v.y;
                }
            }
            const float* wp = &sm.Bs.W[(oc * 4 + ic) * 25];
            #pragma unroll
            for (int ky = 0; ky < 5; ++ky) {
                #pragma unroll
                for (int kx = 0; kx < 5; ++kx) {
                    float wv = wp[ky * 5 + kx];
                    a00 = fmaf(win[ky][kx],     wv, a00);
                    a01 = fmaf(win[ky][kx+1],   wv, a01);
                    a10 = fmaf(win[ky+1][kx],   wv, a10);
                    a11 = fmaf(win[ky+1][kx+1], wv, a11);
                }
            }
        }
        float m = fmaxf(fmaxf(a00, a01), fmaxf(a10, a11));
        c2o[oc * C2H * C2S + i * C2S + j] = fmaxf(m + sm.Bs.B[oc], 0.f);
    }
    grid_barrier(bar + 1);

    // ========== stage C: conv3 + bias + relu + adaptive-max-4x4 ==========
    for (int chunk = blockIdx.x; chunk < 600; chunk += NB) {
        int og = chunk / 60, sb = chunk - og * 60, oc0 = og * 4;
        __syncthreads();
        if (tid < 180) {
            const float* wb = c3w + oc0 * 180 + tid;
            sm.C.W4[tid] = make_float4(wb[0], wb[180], wb[360], wb[540]);
        }
        if (tid < 64) sm.C.bm[tid] = 0;
        __syncthreads();
        int sp = sb * NT + tid;
        if (sp < C3H * C3H) {
            int y = sp / C3H, x = sp - y * C3H;
            float acc0 = 0.f, acc1 = 0.f, acc2 = 0.f, acc3 = 0.f;
            #pragma unroll
            for (int ic = 0; ic < 20; ++ic) {
                const float* ip = c2o + ic * C2H * C2S + y * C2S + x;
                float v[3][3];
                #pragma unroll
                for (int ky = 0; ky < 3; ++ky)
                    #pragma unroll
                    for (int kx = 0; kx < 3; ++kx)
                        v[ky][kx] = ip[ky * C2S + kx];
                #pragma unroll
                for (int kk = 0; kk < 9; ++kk) {
                    float4 wv = sm.C.W4[ic * 9 + kk];
                    float iv = v[kk / 3][kk % 3];
                    acc0 = fmaf(iv, wv.x, acc0);
                    acc1 = fmaf(iv, wv.y, acc1);
                    acc2 = fmaf(iv, wv.z, acc2);
                    acc3 = fmaf(iv, wv.w, acc3);
                }
            }
            acc0 = fmaxf(acc0 + c3b[oc0 + 0], 0.f);
            acc1 = fmaxf(acc1 + c3b[oc0 + 1], 0.f);
            acc2 = fmaxf(acc2 + c3b[oc0 + 2], 0.f);
            acc3 = fmaxf(acc3 + c3b[oc0 + 3], 0.f);
            const int bs[4] = {0, 30, 61, 92};
            const int be[4] = {31, 62, 93, 123};
            #pragma unroll
            for (int yb = 0; yb < 4; ++yb) {
                if (y >= bs[yb] && y < be[yb]) {
                    #pragma unroll
                    for (int xb = 0; xb < 4; ++xb) {
                        if (x >= bs[xb] && x < be[xb]) {
                            int bin = yb * 4 + xb;
                            atomicMax(&sm.C.bm[0 * 16 + bin], __float_as_int(acc0));
                            atomicMax(&sm.C.bm[1 * 16 + bin], __float_as_int(acc1));
                            atomicMax(&sm.C.bm[2 * 16 + bin], __float_as_int(acc2));
                            atomicMax(&sm.C.bm[3 * 16 + bin], __float_as_int(acc3));
                        }
                    }
                }
            }
        }
        __syncthreads();
        if (tid < 64) {
            int v = sm.C.bm[tid];
            if (v != 0)
                atomicMax((int*)&am[(oc0 + (tid >> 4)) * 16 + (tid & 15)], v);
        }
    }
    grid_barrier(bar + 2);

    // ================= stage D: fc1+relu+fc2 (block 0 only) ==============
    if (blockIdx.x != 0) return;
    for (int e = tid; e < 640; e += NT) sm.D.hh[e] = am[e];
    __syncthreads();
    {
        int r = tid >> 2, q = tid & 3;
        const float4* wr = (const float4*)(f1w + r * 640 + q * 160);
        const float*  hp = sm.D.hh + q * 160;
        float acc = 0.f;
        #pragma unroll 4
        for (int n = 0; n < 40; ++n) {
            float4 wv = wr[n];
            acc = fmaf(wv.x, hp[n*4+0], acc);
            acc = fmaf(wv.y, hp[n*4+1], acc);
            acc = fmaf(wv.z, hp[n*4+2], acc);
            acc = fmaf(wv.w, hp[n*4+3], acc);
        }
        acc += __shfl_xor(acc, 1, 64);
        acc += __shfl_xor(acc, 2, 64);
        if (q == 0) sm.D.h1[r] = fmaxf(acc + f1b[r], 0.f);
    }
    __syncthreads();
    if (tid < 10) {
        float o = f2b[tid];
        #pragma unroll 8
        for (int n = 0; n < 64; ++n) o = fmaf(sm.D.h1[n], f2w[tid * 64 + n], o);
        out[tid] = o;
    }
}

// ---------------------------------------------------------------------------
extern "C" void kernel_launch(void* const* d_in, const int* in_sizes, int n_in,
                              void* d_out, int out_size, void* d_ws, size_t ws_size,
                              hipStream_t stream) {
    const float* x   = (const float*)d_in[0];
    const float* qw  = (const float*)d_in[1];
    const float* c2w = (const float*)d_in[2];
    const float* c2b = (const float*)d_in[3];
    const float* c3w = (const float*)d_in[4];
    const float* c3b = (const float*)d_in[5];
    const float* f1w = (const float*)d_in[6];
    const float* f1b = (const float*)d_in[7];
    const float* f2w = (const float*)d_in[8];
    const float* f2b = (const float*)d_in[9];

    // zero barrier state (16 ints) + am bins (640 floats)
    hipMemsetAsync(d_ws, 0, (16 + 640) * sizeof(float), stream);
    fused_net<<<NB, NT, 0, stream>>>(x, qw, c2w, c2b, c3w, c3b,
                                     f1w, f1b, f2w, f2b,
                                     (float*)d_ws, (float*)d_out);
}

// Round 9
// 139.876 us; speedup vs baseline: 1.5771x; 1.5771x over previous
//
#include <hip/hip_runtime.h>
#include <math.h>

#define IMG 512
#define QO  255      // qconv pooled output dim
#define QP  256      // padded row stride of qout
#define C2H 125
#define C2S 128      // padded row stride of c2out
#define C3H 123

// ---------------------------------------------------------------------------
// Register-level circuit evolution helpers (compile-time gate wiring).
// ---------------------------------------------------------------------------
template<int M_>
__device__ inline void rot_regs(float2* a, float2 U00, float2 U01, float2 U10, float2 U11) {
    #pragma unroll
    for (int s = 0; s < 16; ++s) {
        if (!(s & M_)) {
            float2 a0 = a[s], a1 = a[s | M_];
            a[s]      = make_float2(U00.x*a0.x - U00.y*a0.y + U01.x*a1.x - U01.y*a1.y,
                                    U00.x*a0.y + U00.y*a0.x + U01.x*a1.y + U01.y*a1.x);
            a[s | M_] = make_float2(U10.x*a0.x - U10.y*a0.y + U11.x*a1.x - U11.y*a1.y,
                                    U10.x*a0.y + U10.y*a0.x + U11.x*a1.y + U11.y*a1.x);
        }
    }
}
template<int MC, int MT>
__device__ inline void cnot_regs(float2* a) {
    #pragma unroll
    for (int s = 0; s < 16; ++s) {
        if ((s & MC) && !(s & MT)) {
            float2 t = a[s]; a[s] = a[s | MT]; a[s | MT] = t;
        }
    }
}
__device__ inline void rot_gate_params(float phi, float th, float om,
                                       float2& U00, float2& U01, float2& U10, float2& U11) {
    float ch, sh, ca, sa, cb, sb;
    __sincosf(0.5f * th, &sh, &ch);
    __sincosf(0.5f * (phi + om), &sa, &ca);
    __sincosf(0.5f * (phi - om), &sb, &cb);
    U00 = make_float2( ca*ch, -sa*ch);
    U01 = make_float2(-cb*sh, -sb*sh);
    U10 = make_float2( cb*sh, -sb*sh);
    U11 = make_float2( ca*ch,  sa*ch);
}

__device__ __constant__ int UP1[10] = {0,0,0,0,1,1,1,2,2,3};
__device__ __constant__ int UP2[10] = {0,1,2,3,1,2,3,2,3,3};

// ---------------------------------------------------------------------------
// build_G: one small block. Evolve M in registers (16 threads), fold the
// RX phases, then build the folded real bilinear tensor
//   G[al][be].w = sum_r ±Re( conj(Msym_r[al]) * Msym_r[be] )
// (10x10 over the distinct symmetric pair products), write 100 float4 to ws.
// ---------------------------------------------------------------------------
__global__ void build_G(const float* __restrict__ qw, float4* __restrict__ gG) {
    __shared__ float2 Ms[256];
    int tid = threadIdx.x;
    if (tid < 16) {
        float2 a[16];
        #pragma unroll
        for (int s = 0; s < 16; ++s) a[s] = make_float2(s == tid ? 1.f : 0.f, 0.f);
        float2 U00, U01, U10, U11;
#define ROTG(L, W) rot_gate_params(qw[((L)*4+(W))*3+0], qw[((L)*4+(W))*3+1], qw[((L)*4+(W))*3+2], U00,U01,U10,U11); \
                   rot_regs<(1 << (3-(W)))>(a, U00, U01, U10, U11);
        ROTG(0,0) ROTG(0,1) ROTG(0,2) ROTG(0,3)
        cnot_regs<8,4>(a); cnot_regs<4,2>(a); cnot_regs<2,1>(a); cnot_regs<1,8>(a);
        ROTG(1,0) ROTG(1,1) ROTG(1,2) ROTG(1,3)
        cnot_regs<8,2>(a); cnot_regs<4,1>(a); cnot_regs<2,8>(a); cnot_regs<1,4>(a);
        ROTG(2,0) ROTG(2,1) ROTG(2,2) ROTG(2,3)
        cnot_regs<8,1>(a); cnot_regs<4,8>(a); cnot_regs<2,4>(a); cnot_regs<1,2>(a);
#undef ROTG
        int pc4 = __popc(tid) & 3;
        #pragma unroll
        for (int row = 0; row < 16; ++row) {
            float2 v = a[row], o;
            if      (pc4 == 0) o = v;
            else if (pc4 == 1) o = make_float2( v.y, -v.x);
            else if (pc4 == 2) o = make_float2(-v.x, -v.y);
            else               o = make_float2(-v.y,  v.x);
            Ms[row * 16 + tid] = o;
        }
    }
    __syncthreads();
    if (tid < 100) {
        int al = tid / 10, be = tid - 10 * (tid / 10);
        int u = UP1[al], up = UP2[al], v = UP1[be], vp = UP2[be];
        float s0 = 0.f, s1 = 0.f, s2 = 0.f, s3 = 0.f;
        for (int ci = 0; ci < 2; ++ci) {
            if (ci == 1 && u == up) break;
            int a1 = ci ? up : u, a2 = ci ? u : up;
            for (int cj = 0; cj < 2; ++cj) {
                if (cj == 1 && v == vp) break;
                int b1 = cj ? vp : v, b2 = cj ? v : vp;
                int k = a1 * 4 + b1, kp = a2 * 4 + b2;
                #pragma unroll
                for (int r = 0; r < 16; ++r) {
                    float2 m1 = Ms[r * 16 + k], m2 = Ms[r * 16 + kp];
                    float p = m1.x * m2.x + m1.y * m2.y;
                    s0 += (r & 8) ? -p : p;
                    s1 += (r & 4) ? -p : p;
                    s2 += (r & 2) ? -p : p;
                    s3 += (r & 1) ? -p : p;
                }
            }
        }
        gG[tid] = make_float4(s0, s1, s2, s3);
    }
}

// ---------------------------------------------------------------------------
// qconv + sigmoid∘maxpool2. ONE THREAD PER PATCH (4 per pooled pixel,
// 260100 threads = 16 waves/CU), pool via shfl_xor over the 4-lane group.
// ez_w(patch) = sum_{al,be} G[al][be].w * q01[al] * q23[be].
// out: [4][QP][QP] padded.
// ---------------------------------------------------------------------------
__global__ __launch_bounds__(256) void qconv_pool(const float* __restrict__ img,
                                                  const float4* __restrict__ gG,
                                                  float* __restrict__ out) {
    __shared__ float4 G4[100];
    int tid = threadIdx.x;
    if (tid < 100) G4[tid] = gG[tid];
    __syncthreads();

    int gid = blockIdx.x * 256 + tid;
    int pixel = gid >> 2, p = gid & 3;
    if (pixel >= QO * QO) return;
    int i = pixel / QO, j = pixel - i * QO;
    int pr = p >> 1, pc = p & 1;
    const float* ip = img + (2 * i + pr) * IMG + (2 * j + pc);

    float x00 = ip[0], x01 = ip[1], x10 = ip[IMG], x11 = ip[IMG + 1];
    float s0, c0, s1, c1, s2, c2, s3, c3;
    __sincosf(0.5f * x00, &s0, &c0);
    __sincosf(0.5f * x01, &s1, &c1);
    __sincosf(0.5f * x10, &s2, &c2);
    __sincosf(0.5f * x11, &s3, &c3);

    float t01[4] = {c0 * c1, c0 * s1, s0 * c1, s0 * s1};
    float t23[4] = {c2 * c3, c2 * s3, s2 * c3, s2 * s3};
    float q01[10], q23[10];
    #pragma unroll
    for (int al = 0; al < 10; ++al) q01[al] = t01[UP1[al]] * t01[UP2[al]];
    #pragma unroll
    for (int be = 0; be < 10; ++be) q23[be] = t23[UP1[be]] * t23[UP2[be]];

    float e0 = 0.f, e1 = 0.f, e2 = 0.f, e3 = 0.f;
    #pragma unroll
    for (int al = 0; al < 10; ++al) {
        float pa = q01[al];
        #pragma unroll
        for (int be = 0; be < 10; ++be) {
            float4 g = G4[al * 10 + be];     // uniform LDS broadcast
            float pq = pa * q23[be];
            e0 = fmaf(g.x, pq, e0);
            e1 = fmaf(g.y, pq, e1);
            e2 = fmaf(g.z, pq, e2);
            e3 = fmaf(g.w, pq, e3);
        }
    }

    // 2x2 maxpool across the 4 patch lanes of this pooled pixel
    e0 = fmaxf(e0, __shfl_xor(e0, 1, 64)); e0 = fmaxf(e0, __shfl_xor(e0, 2, 64));
    e1 = fmaxf(e1, __shfl_xor(e1, 1, 64)); e1 = fmaxf(e1, __shfl_xor(e1, 2, 64));
    e2 = fmaxf(e2, __shfl_xor(e2, 1, 64)); e2 = fmaxf(e2, __shfl_xor(e2, 2, 64));
    e3 = fmaxf(e3, __shfl_xor(e3, 1, 64)); e3 = fmaxf(e3, __shfl_xor(e3, 2, 64));

    if (p == 0) {
        int o = i * QP + j;
        out[0 * QP * QP + o] = 1.f / (1.f + __expf(-e0));
        out[1 * QP * QP + o] = 1.f / (1.f + __expf(-e1));
        out[2 * QP * QP + o] = 1.f / (1.f + __expf(-e2));
        out[3 * QP * QP + o] = 1.f / (1.f + __expf(-e3));
    }
}

// ---------------------------------------------------------------------------
// conv2 (4->20, 5x5) + bias + relu + maxpool2. oc = blockIdx.y; weights in
// LDS (broadcast reads). Zero-inits the adaptive-max bins.
// ---------------------------------------------------------------------------
__global__ __launch_bounds__(256) void conv2_pool(const float* __restrict__ in,
                                                  const float* __restrict__ w,
                                                  const float* __restrict__ b,
                                                  float* __restrict__ out,
                                                  float* __restrict__ am) {
    __shared__ float W[100];
    __shared__ float Bv;
    int oc = blockIdx.y;
    if (threadIdx.x < 100) W[threadIdx.x] = w[oc * 100 + threadIdx.x];
    if (threadIdx.x == 0) Bv = b[oc];
    if (blockIdx.x == 0 && oc == 0) {
        for (int e = threadIdx.x; e < 640; e += 256) am[e] = 0.f;
    }
    __syncthreads();

    int sp = blockIdx.x * 256 + threadIdx.x;
    if (sp >= C2H * C2H) return;
    int i = sp / C2H, j = sp - i * C2H;

    float a00 = 0.f, a01 = 0.f, a10 = 0.f, a11 = 0.f;
    #pragma unroll
    for (int ic = 0; ic < 4; ++ic) {
        const float* ip = in + ic * QP * QP + (2 * i) * QP + 2 * j;
        float win[6][6];
        #pragma unroll
        for (int y = 0; y < 6; ++y) {
            #pragma unroll
            for (int h = 0; h < 3; ++h) {
                float2 v = *(const float2*)(ip + y * QP + 2 * h);
                win[y][2*h]   = v.x;
                win[y][2*h+1] = v.y;
            }
        }
        #pragma unroll
        for (int ky = 0; ky < 5; ++ky) {
            #pragma unroll
            for (int kx = 0; kx < 5; ++kx) {
                float wv = W[ic * 25 + ky * 5 + kx];   // LDS broadcast
                a00 = fmaf(win[ky][kx],     wv, a00);
                a01 = fmaf(win[ky][kx+1],   wv, a01);
                a10 = fmaf(win[ky+1][kx],   wv, a10);
                a11 = fmaf(win[ky+1][kx+1], wv, a11);
            }
        }
    }
    float m = fmaxf(fmaxf(a00, a01), fmaxf(a10, a11));
    out[oc * C2H * C2S + i * C2S + j] = fmaxf(m + Bv, 0.f);
}

// ---------------------------------------------------------------------------
// conv3 (20->40, 3x3) + bias + relu fused with adaptive-max-4x4.
// og = blockIdx.y owns 4 output channels; weights packed float4 in LDS.
// LDS per-block bins -> device atomicMax (float-as-int, valid for relu >= 0).
// ---------------------------------------------------------------------------
__global__ __launch_bounds__(256) void conv3_amax(const float* __restrict__ in,
                                                  const float* __restrict__ w,
                                                  const float* __restrict__ b,
                                                  int* __restrict__ am) {
    __shared__ float4 W4[180];
    __shared__ int bm[64];   // [ocl 0..3][bin 0..15]
    int og = blockIdx.y, oc0 = og * 4;
    if (threadIdx.x < 180) {
        const float* wb = w + oc0 * 180 + threadIdx.x;
        W4[threadIdx.x] = make_float4(wb[0], wb[180], wb[360], wb[540]);
    }
    if (threadIdx.x < 64) bm[threadIdx.x] = 0;
    __syncthreads();

    int sp = blockIdx.x * 256 + threadIdx.x;
    if (sp < C3H * C3H) {
        int y = sp / C3H, x = sp - y * C3H;

        float acc0 = 0.f, acc1 = 0.f, acc2 = 0.f, acc3 = 0.f;
        #pragma unroll
        for (int ic = 0; ic < 20; ++ic) {
            const float* ip = in + ic * C2H * C2S + y * C2S + x;
            float v[3][3];
            #pragma unroll
            for (int ky = 0; ky < 3; ++ky)
                #pragma unroll
                for (int kx = 0; kx < 3; ++kx)
                    v[ky][kx] = ip[ky * C2S + kx];
            #pragma unroll
            for (int kk = 0; kk < 9; ++kk) {
                float4 wv = W4[ic * 9 + kk];        // LDS broadcast
                float iv = v[kk / 3][kk % 3];
                acc0 = fmaf(iv, wv.x, acc0);
                acc1 = fmaf(iv, wv.y, acc1);
                acc2 = fmaf(iv, wv.z, acc2);
                acc3 = fmaf(iv, wv.w, acc3);
            }
        }
        acc0 = fmaxf(acc0 + b[oc0 + 0], 0.f);
        acc1 = fmaxf(acc1 + b[oc0 + 1], 0.f);
        acc2 = fmaxf(acc2 + b[oc0 + 2], 0.f);
        acc3 = fmaxf(acc3 + b[oc0 + 3], 0.f);

        // adaptive bins: start {0,30,61,92}, end {31,62,93,123} (overlapping)
        const int bs[4] = {0, 30, 61, 92};
        const int be[4] = {31, 62, 93, 123};
        #pragma unroll
        for (int yb = 0; yb < 4; ++yb) {
            if (y >= bs[yb] && y < be[yb]) {
                #pragma unroll
                for (int xb = 0; xb < 4; ++xb) {
                    if (x >= bs[xb] && x < be[xb]) {
                        int bin = yb * 4 + xb;
                        atomicMax(&bm[0 * 16 + bin], __float_as_int(acc0));
                        atomicMax(&bm[1 * 16 + bin], __float_as_int(acc1));
                        atomicMax(&bm[2 * 16 + bin], __float_as_int(acc2));
                        atomicMax(&bm[3 * 16 + bin], __float_as_int(acc3));
                    }
                }
            }
        }
    }
    __syncthreads();
    if (threadIdx.x < 64) {
        int v = bm[threadIdx.x];
        if (v != 0)
            atomicMax(&am[(oc0 + (threadIdx.x >> 4)) * 16 + (threadIdx.x & 15)], v);
    }
}

// ---------------------------------------------------------------------------
// fc1 (640->64) + relu + fc2 (64->10). 256 threads: 4 lanes per fc1 row.
// ---------------------------------------------------------------------------
__global__ void fc_k(const float* __restrict__ h, const float* __restrict__ w1,
                     const float* __restrict__ b1, const float* __restrict__ w2,
                     const float* __restrict__ b2, float* __restrict__ out) {
    __shared__ float hh[640];
    __shared__ float h1[64];
    int t = threadIdx.x;   // 256
    for (int e = t; e < 640; e += 256) hh[e] = h[e];
    __syncthreads();

    int r = t >> 2, q = t & 3;
    const float4* wr = (const float4*)(w1 + r * 640 + q * 160);
    const float*  hp = hh + q * 160;
    float acc = 0.f;
    #pragma unroll 4
    for (int n = 0; n < 40; ++n) {
        float4 wv = wr[n];
        acc = fmaf(wv.x, hp[n*4+0], acc);
        acc = fmaf(wv.y, hp[n*4+1], acc);
        acc = fmaf(wv.z, hp[n*4+2], acc);
        acc = fmaf(wv.w, hp[n*4+3], acc);
    }
    acc += __shfl_xor(acc, 1, 64);
    acc += __shfl_xor(acc, 2, 64);
    if (q == 0) h1[r] = fmaxf(acc + b1[r], 0.f);
    __syncthreads();

    if (t < 10) {
        float o = b2[t];
        #pragma unroll 8
        for (int n = 0; n < 64; ++n) o = fmaf(h1[n], w2[t * 64 + n], o);
        out[t] = o;
    }
}

// ---------------------------------------------------------------------------
extern "C" void kernel_launch(void* const* d_in, const int* in_sizes, int n_in,
                              void* d_out, int out_size, void* d_ws, size_t ws_size,
                              hipStream_t stream) {
    const float* x   = (const float*)d_in[0];
    const float* qw  = (const float*)d_in[1];
    const float* c2w = (const float*)d_in[2];
    const float* c2b = (const float*)d_in[3];
    const float* c3w = (const float*)d_in[4];
    const float* c3b = (const float*)d_in[5];
    const float* f1w = (const float*)d_in[6];
    const float* f1b = (const float*)d_in[7];
    const float* f2w = (const float*)d_in[8];
    const float* f2b = (const float*)d_in[9];
    float* out = (float*)d_out;

    float* wsf   = (float*)d_ws;
    float4* gG   = (float4*)d_ws;                    // 100 float4 = 1.6 KB
    float* am    = wsf + 400;                        // 640 floats
    float* qout  = am + 640;                         // [4][256][256]  1 MB
    float* c2out = qout + 4 * QP * QP;               // [20][125][128] 1.28 MB

    build_G<<<1, 128, 0, stream>>>(qw, gG);
    qconv_pool<<<(4 * QO * QO + 255) / 256, 256, 0, stream>>>(x, gG, qout);
    conv2_pool<<<dim3((C2H * C2H + 255) / 256, 20), 256, 0, stream>>>(qout, c2w, c2b, c2out, am);
    conv3_amax<<<dim3((C3H * C3H + 255) / 256, 10), 256, 0, stream>>>(c2out, c3w, c3b, (int*)am);
    fc_k<<<1, 256, 0, stream>>>(am, f1w, f1b, f2w, f2b, out);
}